// Round 8
// baseline (744.695 us; speedup 1.0000x reference)
//
#include <hip/hip_runtime.h>

#define Dn 512
#define Bn 32
#define Tn 2048
#define BT 65536   // Bn*Tn

typedef unsigned short u16;
typedef __attribute__((ext_vector_type(8))) short short8;   // 8 bf16 = 4 VGPRs (MFMA A/B frag)
typedef __attribute__((ext_vector_type(4))) float floatx4;  // MFMA C/D frag

__device__ __forceinline__ u16 f2bf(float f) {
    unsigned u = __float_as_uint(f);
    unsigned r = (u + 0x7FFFu + ((u >> 16) & 1u)) >> 16;    // RNE
    return (u16)r;
}
__device__ __forceinline__ float bf2f(u16 s) { return __uint_as_float(((unsigned)s) << 16); }

// async global->LDS, 16B/lane, LDS dest = wave-uniform base + lane*16
#define GLD16(gp, lp) __builtin_amdgcn_global_load_lds( \
    (const __attribute__((address_space(1))) unsigned int*)(gp), \
    (__attribute__((address_space(3))) unsigned int*)(lp), 16, 0, 0)

// Preprocessor repeat lists (r1-r6 lessons: indexed arrays -> scratch; LDS
// working sets -> issue-bound; batched shfl/loads before fma pass).
#define REP64(X) X(0) X(1) X(2) X(3) X(4) X(5) X(6) X(7) X(8) X(9) X(10) X(11) X(12) X(13) X(14) X(15) \
    X(16) X(17) X(18) X(19) X(20) X(21) X(22) X(23) X(24) X(25) X(26) X(27) X(28) X(29) X(30) X(31) \
    X(32) X(33) X(34) X(35) X(36) X(37) X(38) X(39) X(40) X(41) X(42) X(43) X(44) X(45) X(46) X(47) \
    X(48) X(49) X(50) X(51) X(52) X(53) X(54) X(55) X(56) X(57) X(58) X(59) X(60) X(61) X(62) X(63)
#define REPJ(OP, K) OP(K,0) OP(K,1) OP(K,2) OP(K,3) OP(K,4) OP(K,5) OP(K,6) OP(K,7) OP(K,8) OP(K,9) \
    OP(K,10) OP(K,11) OP(K,12) OP(K,13) OP(K,14) OP(K,15) OP(K,16) OP(K,17) OP(K,18) OP(K,19) \
    OP(K,20) OP(K,21) OP(K,22) OP(K,23) OP(K,24) OP(K,25) OP(K,26) OP(K,27) OP(K,28) OP(K,29) \
    OP(K,30) OP(K,31) OP(K,32) OP(K,33) OP(K,34) OP(K,35) OP(K,36) OP(K,37) OP(K,38) OP(K,39) \
    OP(K,40) OP(K,41) OP(K,42) OP(K,43) OP(K,44) OP(K,45) OP(K,46) OP(K,47) OP(K,48) OP(K,49) \
    OP(K,50) OP(K,51) OP(K,52) OP(K,53) OP(K,54) OP(K,55) OP(K,56) OP(K,57) OP(K,58) OP(K,59) \
    OP(K,60) OP(K,61) OP(K,62) OP(K,63)
// 64 (M, Mq=M/4, e=M%4) triples with a carried C
#define REPQ(OP, C) OP(C,0,0,0) OP(C,1,0,1) OP(C,2,0,2) OP(C,3,0,3) OP(C,4,1,0) OP(C,5,1,1) OP(C,6,1,2) OP(C,7,1,3) \
    OP(C,8,2,0) OP(C,9,2,1) OP(C,10,2,2) OP(C,11,2,3) OP(C,12,3,0) OP(C,13,3,1) OP(C,14,3,2) OP(C,15,3,3) \
    OP(C,16,4,0) OP(C,17,4,1) OP(C,18,4,2) OP(C,19,4,3) OP(C,20,5,0) OP(C,21,5,1) OP(C,22,5,2) OP(C,23,5,3) \
    OP(C,24,6,0) OP(C,25,6,1) OP(C,26,6,2) OP(C,27,6,3) OP(C,28,7,0) OP(C,29,7,1) OP(C,30,7,2) OP(C,31,7,3) \
    OP(C,32,8,0) OP(C,33,8,1) OP(C,34,8,2) OP(C,35,8,3) OP(C,36,9,0) OP(C,37,9,1) OP(C,38,9,2) OP(C,39,9,3) \
    OP(C,40,10,0) OP(C,41,10,1) OP(C,42,10,2) OP(C,43,10,3) OP(C,44,11,0) OP(C,45,11,1) OP(C,46,11,2) OP(C,47,11,3) \
    OP(C,48,12,0) OP(C,49,12,1) OP(C,50,12,2) OP(C,51,12,3) OP(C,52,13,0) OP(C,53,13,1) OP(C,54,13,2) OP(C,55,13,3) \
    OP(C,56,14,0) OP(C,57,14,1) OP(C,58,14,2) OP(C,59,14,3) OP(C,60,15,0) OP(C,61,15,1) OP(C,62,15,2) OP(C,63,15,3)
// 16 (Q, 4Q, 4Q+1, 4Q+2, 4Q+3) groups
#define REPW(OP) OP(0,0,1,2,3) OP(1,4,5,6,7) OP(2,8,9,10,11) OP(3,12,13,14,15) OP(4,16,17,18,19) \
    OP(5,20,21,22,23) OP(6,24,25,26,27) OP(7,28,29,30,31) OP(8,32,33,34,35) OP(9,36,37,38,39) \
    OP(10,40,41,42,43) OP(11,44,45,46,47) OP(12,48,49,50,51) OP(13,52,53,54,55) OP(14,56,57,58,59) \
    OP(15,60,61,62,63)
#define REP16C(OP, C) OP(C,0) OP(C,1) OP(C,2) OP(C,3) OP(C,4) OP(C,5) OP(C,6) OP(C,7) \
    OP(C,8) OP(C,9) OP(C,10) OP(C,11) OP(C,12) OP(C,13) OP(C,14) OP(C,15)

// ---------------------------------------------------------------------------
// 1) x[b][t][d] (f32) -> Xt[d][b*Tn+t] (bf16), LDS 64x64 tile transpose.
// ---------------------------------------------------------------------------
__global__ __launch_bounds__(256) void k_transpose(const float* __restrict__ x,
                                                   u16* __restrict__ Xt) {
    int tt = blockIdx.x;   // t-tile 0..31
    int dt = blockIdx.y;   // d-tile 0..7
    int b  = blockIdx.z;   // 0..31
    __shared__ u16 sT[64][68];  // [d][t], padded
    int tid = threadIdx.x;
    int row = tid >> 4;            // 0..15 (t)
    int c4  = (tid & 15) * 4;      // 0..60 (d)
    const float* src = x + ((long)b * Tn + (long)tt * 64) * Dn + dt * 64;
#pragma unroll
    for (int q = 0; q < 4; q++) {
        int r = row + q * 16;
        floatx4 v = *(const floatx4*)(src + (long)r * Dn + c4);
        sT[c4 + 0][r] = f2bf(v[0]);
        sT[c4 + 1][r] = f2bf(v[1]);
        sT[c4 + 2][r] = f2bf(v[2]);
        sT[c4 + 3][r] = f2bf(v[3]);
    }
    __syncthreads();
    int drow = tid >> 3;           // 0..31 (d)
    int koff = (tid & 7) * 8;      // 0..56 (t)
    long kout = (long)b * Tn + (long)tt * 64 + koff;
#pragma unroll
    for (int p = 0; p < 2; p++) {
        int dr = drow + p * 32;
        u16 tmp[8];
#pragma unroll
        for (int j = 0; j < 8; j++) tmp[j] = sT[dr][koff + j];
        *(short8*)(Xt + (long)(dt * 64 + dr) * BT + kout) = *(short8*)tmp;
    }
}

// ---------------------------------------------------------------------------
// 2) mu[b][d] = (1/T) sum_t Xt[d][b*Tn+t]   (wave per (b,d))
// ---------------------------------------------------------------------------
__global__ __launch_bounds__(256) void k_mu(const u16* __restrict__ Xt,
                                            float* __restrict__ mu) {
    int tid = threadIdx.x;
    int wave = tid >> 6, lane = tid & 63;
    int p = blockIdx.x * 4 + wave;      // 0..16383 == b*512+d
    int b = p >> 9, d = p & 511;
    const u16* src = Xt + (long)d * BT + (long)b * Tn;
    float s = 0.f;
#pragma unroll
    for (int c = 0; c < 4; c++) {
        short8 v = *(const short8*)(src + c * 512 + lane * 8);
#pragma unroll
        for (int j = 0; j < 8; j++) s += bf2f((u16)v[j]);
    }
#pragma unroll
    for (int off = 32; off; off >>= 1) s += __shfl_down(s, off, 64);
    if (lane == 0) mu[p] = s * (1.0f / Tn);
}

// ---------------------------------------------------------------------------
// 3) Gram partials. Round-8: 64 K-chunks (K=1024) x 10 sym positions = 640
//    blocks (~2.5/CU, was 160 = 1 wave/SIMD, Occupancy 6.5%); m97-style
//    global_load_lds width-16 staging into UNPADDED K-major LDS (16 KB).
// ---------------------------------------------------------------------------
__global__ __launch_bounds__(256) void k_gram(const u16* __restrict__ Xt,
                                              float* __restrict__ partial) {
    int chunk = blockIdx.x;             // 0..63 (K-chunk of 1024)
    int pos = blockIdx.y;               // 0..9 upper-block-triangle positions
    int di = (pos < 4) ? 0 : (pos < 7) ? 1 : (pos < 9) ? 2 : 3;
    int start = di * 4 - (di * (di - 1)) / 2;   // 0,4,7,9
    int ei = di + (pos - start);
    int d0 = di * 128, e0 = ei * 128;
    long cb = (long)chunk << 10;        // K window base

    __shared__ u16 sA[128 * 32];
    __shared__ u16 sB[128 * 32];
    int tid = threadIdx.x;
    int wave = tid >> 6, lane = tid & 63;
    int wm = wave & 1, wn = wave >> 1;  // 2x2 waves over 128x128
    int m = lane & 15, g = lane >> 4;

    // staging: wave w covers rows [w*32, w*32+32), 16 rows (1 KB) per GLD16
    const u16* gA0 = Xt + (long)(d0 + wave * 32 + (lane >> 2)) * BT + cb + (lane & 3) * 8;
    const u16* gB0 = Xt + (long)(e0 + wave * 32 + (lane >> 2)) * BT + cb + (lane & 3) * 8;
    u16* lA = sA + wave * 1024;         // (w*32 rows) * 32 elem
    u16* lB = sB + wave * 1024;

    floatx4 acc[4][4] = {};
    for (int kk = 0; kk < 1024; kk += 32) {
        __syncthreads();                          // prior iter's LDS reads done
        GLD16(gA0 + kk, lA);
        GLD16(gA0 + 16l * BT + kk, lA + 512);
        GLD16(gB0 + kk, lB);
        GLD16(gB0 + 16l * BT + kk, lB + 512);
        __syncthreads();                          // drains vmcnt -> data landed
        short8 af[4], bf[4];
#pragma unroll
        for (int i = 0; i < 4; i++)
            af[i] = *(const short8*)(sA + (wm * 64 + i * 16 + m) * 32 + g * 8);
#pragma unroll
        for (int j = 0; j < 4; j++)
            bf[j] = *(const short8*)(sB + (wn * 64 + j * 16 + m) * 32 + g * 8);
#pragma unroll
        for (int i = 0; i < 4; i++)
#pragma unroll
            for (int j = 0; j < 4; j++)
                acc[i][j] = __builtin_amdgcn_mfma_f32_16x16x32_bf16(af[i], bf[j], acc[i][j], 0, 0, 0);
    }
    // C/D layout: col = lane&15, row = (lane>>4)*4 + reg   [m89-verified]
    float* P = partial + (long)chunk * (512l * 512);
    int col = lane & 15, rowg = (lane >> 4) * 4;
#pragma unroll
    for (int i = 0; i < 4; i++)
#pragma unroll
        for (int j = 0; j < 4; j++) {
            int rr = d0 + wm * 64 + i * 16 + rowg;
            int cc = e0 + wn * 64 + j * 16 + col;
#pragma unroll
            for (int r = 0; r < 4; r++) P[(long)(rr + r) * 512 + cc] = acc[i][j][r];
        }
}

// ---------------------------------------------------------------------------
// 4) cov[d][e] = (G[d][e] - T * sum_b mu[b,d]*mu[b,e]) / ((T-1)*B)
// ---------------------------------------------------------------------------
__global__ __launch_bounds__(256) void k_assemble(const float* __restrict__ partial,
                                                  const float* __restrict__ mu,
                                                  float* __restrict__ A) {
    int d = blockIdx.y;
    int e = blockIdx.x * 256 + threadIdx.x;
    int bd = d >> 7, be = e >> 7;
    long idx = (bd <= be) ? ((long)d * 512 + e) : ((long)e * 512 + d);  // symmetric mirror
    float s = 0.f;
#pragma unroll 8
    for (int c = 0; c < 64; c++) s += partial[c * (512l * 512) + idx];
    float msum = 0.f;
#pragma unroll
    for (int b = 0; b < 32; b++) msum += mu[b * 512 + d] * mu[b * 512 + e];
    A[(long)d * 512 + e] = (s - (float)Tn * msum) * (1.0f / ((Tn - 1.0f) * Bn));
}

// ---------------------------------------------------------------------------
// 5) LEFT-LOOKING Cholesky panel (one launch per kb; replaces panel+update).
//    Block bi handles rows r0 = k0 + bi*64 (bi=0 -> diag itself).
//    Phase 1 (256 thr): accD/accS = A tiles minus sum over prior panels
//      L[.,kc]*Ld[.,kc]^T (k_chol_update-style 4x4 register tiles).
//    Phase 2 (wave 0): factor updated diag in NAMED regs, batched shuffles.
//    Phase 3 (wave 0): bi==0 writes diag; bi>0 solves its 64-row stripe
//      (r7 batched-b128 TSTEP) and writes L21.
// ---------------------------------------------------------------------------
__global__ __launch_bounds__(256, 1) void k_chol_left(float* __restrict__ A, int kb) {
    const int k0 = kb * 64;
    const int bi = blockIdx.x;
    const int r0 = k0 + bi * 64;
    const int tid = threadIdx.x;
    const int lane = tid & 63;
    const int wv = tid >> 6;
    __shared__ float sLd[64 * 65];   // diag-rows L panel tile
    __shared__ float sLr[64 * 65];   // stripe-rows L panel tile
    __shared__ float sD[64 * 68];    // updated diag block -> factored L11
    __shared__ float sS[64 * 68];    // updated stripe block
    __shared__ float sInv[64];
    const floatx4 z4 = {0.f, 0.f, 0.f, 0.f};

    int srow = tid >> 4, c4 = (tid & 15) * 4;       // staging map
    int ri = (tid >> 4) * 4, cj = (tid & 15) * 4;   // 4x4 compute map

    // ---- init acc tiles from A ----
    floatx4 accD[4], accS[4];
#pragma unroll
    for (int ii = 0; ii < 4; ii++) {
        accD[ii] = *(const floatx4*)(A + (long)(k0 + ri + ii) * 512 + k0 + cj);
        accS[ii] = *(const floatx4*)(A + (long)(r0 + ri + ii) * 512 + k0 + cj);
    }

    // ---- subtract prior-panel contributions ----
    for (int kc = 0; kc < k0; kc += 64) {
        __syncthreads();
#pragma unroll
        for (int q = 0; q < 4; q++) {
            int rr = srow + q * 16;
            *(floatx4*)&sLd[rr * 65 + c4] = *(const floatx4*)(A + (long)(k0 + rr) * 512 + kc + c4);
            *(floatx4*)&sLr[rr * 65 + c4] = *(const floatx4*)(A + (long)(r0 + rr) * 512 + kc + c4);
        }
        __syncthreads();
        for (int k = 0; k < 64; k += 4) {
            floatx4 ad[4], ar[4], bv[4];
#pragma unroll
            for (int ii = 0; ii < 4; ii++) ad[ii] = *(const floatx4*)&sLd[(ri + ii) * 65 + k];
#pragma unroll
            for (int ii = 0; ii < 4; ii++) ar[ii] = *(const floatx4*)&sLr[(ri + ii) * 65 + k];
#pragma unroll
            for (int jj = 0; jj < 4; jj++) bv[jj] = *(const floatx4*)&sLd[(cj + jj) * 65 + k];
#pragma unroll
            for (int ii = 0; ii < 4; ii++)
#pragma unroll
                for (int jj = 0; jj < 4; jj++)
#pragma unroll
                    for (int q = 0; q < 4; q++) {
                        accD[ii][jj] = fmaf(-ad[ii][q], bv[jj][q], accD[ii][jj]);
                        accS[ii][jj] = fmaf(-ar[ii][q], bv[jj][q], accS[ii][jj]);
                    }
        }
    }

    // ---- park updated tiles in LDS (stride 68 -> rows 16B aligned) ----
#pragma unroll
    for (int ii = 0; ii < 4; ii++) {
        *(floatx4*)&sD[(ri + ii) * 68 + cj] = accD[ii];
        *(floatx4*)&sS[(ri + ii) * 68 + cj] = accS[ii];
    }
    __syncthreads();

    // ---- wave 0: factor diag in named regs, batched shuffles ----
    if (wv == 0) {
        const float* Dr = sD + lane * 68;
#define LDV(Q,A0,A1,A2,A3) floatx4 v##Q = *(const floatx4*)(Dr + 4*(Q));
        REPW(LDV)
#undef LDV
#define DECR(C,M,Mq,e) float r##M = v##Mq[(e)];
        REPQ(DECR, 0)
#undef DECR
        float vinv = 0.f;
#define SH1(K,J) float t##J = ((J) > (K)) ? __shfl(lik, (J), 64) : 0.0f;
#define FM1(K,J) if ((J) > (K)) r##J = fmaf(-lik, t##J, r##J);
#define STEP(K) { float akk = __shfl(r##K, (K), 64); float sd = sqrtf(akk); \
                  float inv = 1.0f / sd; float lik = (lane == (K)) ? sd : r##K * inv; \
                  r##K = lik; if (lane == (K)) vinv = inv; REPJ(SH1, K) REPJ(FM1, K) }
        REP64(STEP)
#undef STEP
#undef FM1
#undef SH1
        // stash L11 + inv for trsm / write diag if bi==0
#define STD(Q,A0,A1,A2,A3) { floatx4 w; w[0]=r##A0; w[1]=r##A1; w[2]=r##A2; w[3]=r##A3; \
                             *(floatx4*)(sD + lane * 68 + 4*(Q)) = w; }
        REPW(STD)
#undef STD
        sInv[lane] = vinv;
        if (bi == 0) {
            float* W = A + (long)(k0 + lane) * 512 + k0;
#define STW(Q,A0,A1,A2,A3) { floatx4 w; w[0]=r##A0; w[1]=r##A1; w[2]=r##A2; w[3]=r##A3; \
                             *(floatx4*)(W + 4*(Q)) = w; }
            REPW(STW)
#undef STW
        }
    }
    __syncthreads();
    if (bi == 0) return;

    // ---- wave 0: TRSM stripe (lane = row), batched b128 L-row loads ----
    if (wv == 0) {
        const float* Sr = sS + lane * 68;
#define LDA(Q,A0,A1,A2,A3) floatx4 u##Q = *(const floatx4*)(Sr + 4*(Q));
        REPW(LDA)
#undef LDA
#define DECA(C,M,Mq,e) float a##M = u##Mq[(e)];
        REPQ(DECA, 0)
#undef DECA
#define LQ(C,Q) floatx4 q##Q = ((C) > 4*(Q)) ? *(const floatx4*)(sD + (C) * 68 + 4*(Q)) : z4;
#define TF(C,M,Mq,e) if ((M) < (C)) acc##e = fmaf(a##M, q##Mq[(e)], acc##e);
#define TSTEP(C) { REP16C(LQ, C) float acc0 = 0.f, acc1 = 0.f, acc2 = 0.f, acc3 = 0.f; \
                   REPQ(TF, C) a##C = (a##C - ((acc0 + acc1) + (acc2 + acc3))) * sInv[(C)]; }
        REP64(TSTEP)
#undef TSTEP
#undef TF
#undef LQ
        float* Wr = A + (long)(r0 + lane) * 512 + k0;
#define STA(Q,A0,A1,A2,A3) { floatx4 w; w[0]=a##A0; w[1]=a##A1; w[2]=a##A2; w[3]=a##A3; \
                             *(floatx4*)(Wr + 4*(Q)) = w; }
        REPW(STA)
#undef STA
    }
}

// ---------------------------------------------------------------------------
// 6) out[i][d] = mean[d] + sum_{e<=d} z[i][e] * L[d][e]
// ---------------------------------------------------------------------------
__global__ __launch_bounds__(512) void k_output(const float* __restrict__ z,
                                                const float* __restrict__ A,
                                                const float* __restrict__ mu,
                                                float* __restrict__ out) {
    int i = blockIdx.x, d = threadIdx.x;
    __shared__ float sz[512];
    sz[d] = z[(long)i * 512 + d];
    __syncthreads();
    float mean = 0.f;
#pragma unroll
    for (int b = 0; b < 32; b++) mean += mu[b * 512 + d];
    mean *= (1.0f / 32.0f);
    const float* Lr = A + (long)d * 512;
    float acc = 0.f;
    int dmax = d + 1;
    int e4 = dmax & ~3;
    for (int e = 0; e < e4; e += 4) {
        floatx4 l = *(const floatx4*)(Lr + e);
        acc += l[0] * sz[e] + l[1] * sz[e + 1] + l[2] * sz[e + 2] + l[3] * sz[e + 3];
    }
    for (int e = e4; e < dmax; e++) acc += Lr[e] * sz[e];
    out[(long)i * 512 + d] = mean + acc;
}

// ---------------------------------------------------------------------------
extern "C" void kernel_launch(void* const* d_in, const int* in_sizes, int n_in,
                              void* d_out, int out_size, void* d_ws, size_t ws_size,
                              hipStream_t stream) {
    const float* x = (const float*)d_in[0];
    const float* z = (const float*)d_in[1];
    float* out = (float*)d_out;
    char* ws = (char*)d_ws;
    // ws layout: Xt 64MB | mu 64KB | partial 64MB | A 1MB
    u16* Xt = (u16*)ws;
    float* mu = (float*)(ws + 67108864);
    float* partial = (float*)(ws + 67108864 + 65536);
    float* A = (float*)(ws + 67108864 + 65536 + 67108864);

    k_transpose<<<dim3(32, 8, 32), 256, 0, stream>>>(x, Xt);
    k_mu<<<4096, 256, 0, stream>>>(Xt, mu);
    k_gram<<<dim3(64, 10), 256, 0, stream>>>(Xt, partial);
    k_assemble<<<dim3(2, 512), 256, 0, stream>>>(partial, mu, A);
    for (int kb = 0; kb < 8; kb++)
        k_chol_left<<<8 - kb, 256, 0, stream>>>(A, kb);
    k_output<<<32, 512, 0, stream>>>(z, A, mu, out);
}